// Round 5
// baseline (575.781 us; speedup 1.0000x reference)
//
#include <hip/hip_runtime.h>
#include <hip/hip_bf16.h>
#include <cstdint>
#include <cstddef>

// Problem constants
#define B_   4
#define S_   2048
#define D_   1024
#define H_   16
#define HD_  64
#define FF_  4096
#define MTOT (B_*S_)   // 8192 rows

typedef __bf16 bf16;
typedef bf16  bf16x8 __attribute__((ext_vector_type(8)));
typedef bf16  bf16x4 __attribute__((ext_vector_type(4)));
typedef float f32x4  __attribute__((ext_vector_type(4)));

#define LOG2E 1.44269504088896340736f

// ---------------------------------------------------------------------------
// async global -> LDS, 16B per lane. LDS dst must be wave-uniform base;
// HW writes base + lane*16. (learn_hip m97 pattern)
// ---------------------------------------------------------------------------
__device__ __forceinline__ void async16(const bf16* g, bf16* l) {
  __builtin_amdgcn_global_load_lds(
      (const __attribute__((address_space(1))) unsigned int*)g,
      (__attribute__((address_space(3))) unsigned int*)l,
      16, 0, 0);
}

// ---------------------------------------------------------------------------
// Weight cast+transpose: W (K x N) fp32 -> Wt (N x K) bf16
// ---------------------------------------------------------------------------
__global__ void wcast_t(const float* __restrict__ W, bf16* __restrict__ Wt,
                        int K, int N) {
  __shared__ float t[32][33];
  const int k0 = blockIdx.y * 32, n0 = blockIdx.x * 32;
  const int tx = threadIdx.x, ty = threadIdx.y;
#pragma unroll
  for (int r = ty; r < 32; r += 8)
    t[r][tx] = W[(size_t)(k0 + r) * N + n0 + tx];
  __syncthreads();
#pragma unroll
  for (int r = ty; r < 32; r += 8)
    Wt[(size_t)(n0 + r) * K + k0 + tx] = (bf16)t[tx][r];
}

// ---------------------------------------------------------------------------
// Fused (residual-add +) LayerNorm -> bf16.  One block per row, 256 thr.
// ---------------------------------------------------------------------------
__global__ void ln_fused(const float* __restrict__ xin, const float* __restrict__ res,
                         const float* __restrict__ gamma, const float* __restrict__ beta,
                         bf16* __restrict__ out) {
  const int row = blockIdx.x, tid = threadIdx.x;
  const int lane = tid & 63, w = tid >> 6;
  f32x4 v = *(const f32x4*)(xin + (size_t)row * D_ + tid * 4);
  if (res) {
    f32x4 r = *(const f32x4*)(res + (size_t)row * D_ + tid * 4);
    v += r;
  }
  float sum = v[0] + v[1] + v[2] + v[3];
  float sq  = v[0]*v[0] + v[1]*v[1] + v[2]*v[2] + v[3]*v[3];
#pragma unroll
  for (int d = 1; d < 64; d <<= 1) {
    sum += __shfl_xor(sum, d);
    sq  += __shfl_xor(sq, d);
  }
  __shared__ float red[8];
  if (lane == 0) { red[w] = sum; red[4 + w] = sq; }
  __syncthreads();
  sum = red[0] + red[1] + red[2] + red[3];
  sq  = red[4] + red[5] + red[6] + red[7];
  const float mu   = sum * (1.f / D_);
  const float rstd = rsqrtf(sq * (1.f / D_) - mu * mu + 1e-5f);
  f32x4 g  = *(const f32x4*)(gamma + tid * 4);
  f32x4 bt = *(const f32x4*)(beta  + tid * 4);
  bf16x4 ov;
#pragma unroll
  for (int j = 0; j < 4; j++)
    ov[j] = (bf16)((v[j] - mu) * rstd * g[j] + bt[j]);
  *(bf16x4*)(out + (size_t)row * D_ + tid * 4) = ov;
}

// ---------------------------------------------------------------------------
// 256x256 GEMM, BK=64, 8 waves (2M x 4N), ring-2 LDS double-buffer with
// COUNTED vmcnt (never drained to 0 in the main loop — T4) and raw s_barrier
// (no compiler vmcnt(0) drain — the m97 ceiling breaker). LDS tiles are
// XOR-swizzled (16B chunk ^= row&7) on BOTH sides: pre-swizzled global
// source + swizzled ds_read_b128 (rule #21) — conflict-free fragment reads.
// XCD-aware block swizzle (T1; all grids divisible by 8).
//
// Schedule per K-tile t:  vmcnt(8) [tile t's 8 loads done; t+1's stay in
// flight] ; barrier ; compute(t) ; barrier ; stage(t+2 -> slot t&1).
// stage(t+2) is safe: slot t&1 readers all passed the trailing barrier.
//
// EPI: 3=ffn1 (bias, relu, bf16)  4=ffn2 (bias + addf residual, fp32)
//      5=qkv (3-sector: q*log2e/8 | k | v->Vt[B,H,HD,S])
// ---------------------------------------------------------------------------
template <int EPI>
__global__ __launch_bounds__(512)
void gemm256(const bf16* __restrict__ A, const bf16* __restrict__ Bt,
             const float* __restrict__ bias, void* __restrict__ Cout,
             const bf16* __restrict__ addf,
             const float* __restrict__ bq, const float* __restrict__ bk,
             const float* __restrict__ bv, bf16* __restrict__ qout,
             bf16* __restrict__ kout, bf16* __restrict__ vtout,
             int M, int N, int K) {
  __shared__ bf16 As[2][256 * 64];   // 32 KiB per slot
  __shared__ bf16 Bs[2][256 * 64];
  const int tid = threadIdx.x;
  const int lane = tid & 63;
  const int w = tid >> 6;            // wave 0..7
  const int wm = w >> 2, wn = w & 3; // 2 x 4 wave grid
  const int rg = lane >> 4, rl = lane & 15;
  const int sr = lane >> 3;          // staging: row within 8-row wave slice
  const int sc = (lane & 7) ^ sr;    // staging: pre-swizzled source chunk

  // XCD-aware swizzle of the linear block id (nwg % 8 == 0 for all callers)
  const int nbn = N >> 8;
  const int cpx = (int)gridDim.x >> 3;
  const int bid = (int)blockIdx.x;
  const int swz = (bid & 7) * cpx + (bid >> 3);
  const int bm = (swz / nbn) << 8;
  const int bn = (swz % nbn) << 8;

  const bf16* gA0 = A  + (size_t)(bm + w * 8 + sr) * K + sc * 8;
  const bf16* gB0 = Bt + (size_t)(bn + w * 8 + sr) * K + sc * 8;
  const size_t i64K = (size_t)64 * K;

#define GSTAGE(slot, t)                                                        \
  {                                                                            \
    const bf16* ga_ = gA0 + (size_t)(t) * 64;                                  \
    const bf16* gb_ = gB0 + (size_t)(t) * 64;                                  \
    _Pragma("unroll")                                                          \
    for (int i_ = 0; i_ < 4; i_++) {                                           \
      async16(ga_ + i_ * i64K, &As[slot][(i_ * 64 + w * 8) * 64]);             \
      async16(gb_ + i_ * i64K, &Bs[slot][(i_ * 64 + w * 8) * 64]);             \
    }                                                                          \
  }

#define COMPUTE(slotbuf)                                                       \
  {                                                                            \
    const bf16* Ac = &As[slotbuf][0];                                          \
    const bf16* Bc = &Bs[slotbuf][0];                                          \
    _Pragma("unroll")                                                          \
    for (int kk = 0; kk < 2; kk++) {                                           \
      bf16x8 af[8], bw[4];                                                     \
      _Pragma("unroll")                                                        \
      for (int mi = 0; mi < 8; mi++)                                           \
        af[mi] = *(const bf16x8*)(Ac + (wm * 128 + mi * 16 + rl) * 64 +        \
                                  (((kk * 4 + rg) ^ (rl & 7)) * 8));           \
      _Pragma("unroll")                                                        \
      for (int ni = 0; ni < 4; ni++)                                           \
        bw[ni] = *(const bf16x8*)(Bc + (wn * 64 + ni * 16 + rl) * 64 +         \
                                  (((kk * 4 + rg) ^ (rl & 7)) * 8));           \
      _Pragma("unroll")                                                        \
      for (int mi = 0; mi < 8; mi++)                                           \
        _Pragma("unroll")                                                      \
        for (int ni = 0; ni < 4; ni++)                                         \
          acc[mi][ni] = __builtin_amdgcn_mfma_f32_16x16x32_bf16(               \
              af[mi], bw[ni], acc[mi][ni], 0, 0, 0);                           \
    }                                                                          \
  }

  f32x4 acc[8][4];
  const f32x4 z = {0.f, 0.f, 0.f, 0.f};
#pragma unroll
  for (int mi = 0; mi < 8; mi++)
#pragma unroll
    for (int ni = 0; ni < 4; ni++) acc[mi][ni] = z;

  const int NT = K >> 6;
  GSTAGE(0, 0);
  GSTAGE(1, 1);

  for (int t = 0; t < NT - 1; ++t) {
    asm volatile("s_waitcnt vmcnt(8)" ::: "memory");   // tile t landed; t+1 in flight
    __builtin_amdgcn_sched_barrier(0);
    __builtin_amdgcn_s_barrier();
    __builtin_amdgcn_sched_barrier(0);
    COMPUTE(t & 1);
    __builtin_amdgcn_sched_barrier(0);
    __builtin_amdgcn_s_barrier();                      // all waves done reading slot t&1
    __builtin_amdgcn_sched_barrier(0);
    if (t + 2 < NT) GSTAGE(t & 1, t + 2);              // overwrite now-dead slot
  }
  asm volatile("s_waitcnt vmcnt(0)" ::: "memory");
  __builtin_amdgcn_sched_barrier(0);
  __builtin_amdgcn_s_barrier();
  __builtin_amdgcn_sched_barrier(0);
  COMPUTE((NT - 1) & 1);

#undef GSTAGE
#undef COMPUTE

  // Epilogue. C/D layout: col = lane&15, row = (lane>>4)*4 + i   [m89/m91]
#pragma unroll
  for (int mi = 0; mi < 8; mi++) {
    const int row0 = bm + wm * 128 + mi * 16 + rg * 4;
#pragma unroll
    for (int ni = 0; ni < 4; ni++) {
      const int col = bn + wn * 64 + ni * 16 + rl;
      if (EPI == 3) {
        const float bb = bias[col];
#pragma unroll
        for (int i = 0; i < 4; i++)
          ((bf16*)Cout)[(size_t)(row0 + i) * N + col] =
              (bf16)fmaxf(acc[mi][ni][i] + bb, 0.f);
      } else if (EPI == 4) {
        const float bb = bias[col];
#pragma unroll
        for (int i = 0; i < 4; i++)
          ((float*)Cout)[(size_t)(row0 + i) * N + col] =
              acc[mi][ni][i] + bb + (float)addf[(size_t)(row0 + i) * N + col];
      } else {  // EPI == 5: qkv sectors
        const int sector = bn >> 10;           // uniform per block (256 | 1024)
        const int cl = col & 1023;
        const float bb = (sector == 0) ? bq[cl] : (sector == 1 ? bk[cl] : bv[cl]);
#pragma unroll
        for (int i = 0; i < 4; i++) {
          const int row = row0 + i;
          const float v = acc[mi][ni][i] + bb;
          if (sector == 0) {
            qout[(size_t)row * D_ + cl] = (bf16)(v * (0.125f * LOG2E));
          } else if (sector == 1) {
            kout[(size_t)row * D_ + cl] = (bf16)v;
          } else {
            const int b = row >> 11, s = row & 2047;
            const int h = cl >> 6, hd = cl & 63;
            vtout[(((size_t)(b * H_ + h) * HD_ + hd) << 11) + s] = (bf16)v;
          }
        }
      }
    }
  }
}

// ---------------------------------------------------------------------------
// Flash attention, swapped-operand, 8 waves / block (QBLK=256, 32 q-rows/wave).
// Grid (S/256, B*H) = (8,64) = 512 blocks = exactly 2 resident blocks/CU.
// (unchanged from round 4 — MfmaUtil 23.7%, 122 µs)
// ---------------------------------------------------------------------------
__global__ __launch_bounds__(512, 4)
void attn_fwd(const bf16* __restrict__ Q, const bf16* __restrict__ Kb,
              const bf16* __restrict__ Vt, float* __restrict__ O) {
  __shared__ bf16 Ks[2][64 * 64];   // [kv][hd], 8KB per buf
  __shared__ bf16 Vs[2][64 * 64];   // [hd][kv], 8KB per buf
  __shared__ bf16 Pl[8][32][72];    // per-wave P^T [q_local][kv], 36KB
  const int tid = threadIdx.x, lane = tid & 63, w = tid >> 6;
  const int rg = lane >> 4, rl = lane & 15;
  const int bh = blockIdx.y, b = bh >> 4, h = bh & 15;
  const int q0 = blockIdx.x * 256 + w * 32;

  const bf16* qp = Q + ((size_t)b * S_ + q0) * D_ + h * HD_;
  const bf16* kp = Kb + (size_t)b * S_ * D_ + h * HD_;
  const bf16* vp = Vt + (size_t)bh * HD_ * S_;

  const int sr = lane >> 3;            // row within the wave's 8-row group
  const int sc = (lane & 7) ^ sr;      // swizzled source 16B chunk

#define STAGE(buf, t)                                                          \
  {                                                                            \
    const int row = w * 8 + sr;                                                \
    async16(kp + (size_t)((t) * 64 + row) * D_ + sc * 8, &Ks[buf][w * 8 * 64]);\
    async16(vp + (size_t)row * S_ + (t) * 64 + sc * 8,  &Vs[buf][w * 8 * 64]); \
  }

  bf16x8 qf[2][2];
#pragma unroll
  for (int m = 0; m < 2; m++)
#pragma unroll
    for (int kc = 0; kc < 2; kc++)
      qf[m][kc] = *(const bf16x8*)(qp + (size_t)(m * 16 + rl) * D_ + kc * 32 + rg * 8);

  const f32x4 z = {0.f, 0.f, 0.f, 0.f};
  f32x4 o[2][4];
  float mr[2], lr[2];
#pragma unroll
  for (int m = 0; m < 2; m++) {
    mr[m] = -1e30f; lr[m] = 0.f;
#pragma unroll
    for (int np = 0; np < 4; np++) o[m][np] = z;
  }

  STAGE(0, 0);
  __syncthreads();

  int cur = 0;
  for (int t = 0; t < S_ / 64; ++t) {
    if (t + 1 < S_ / 64) STAGE(cur ^ 1, t + 1);
    const bf16* Kc = Ks[cur];
    const bf16* Vc = Vs[cur];

    bf16x8 kf[4][2];
#pragma unroll
    for (int n = 0; n < 4; n++) {
      const int krow = n * 16 + rl;
#pragma unroll
      for (int kc = 0; kc < 2; kc++)
        kf[n][kc] = *(const bf16x8*)(Kc + krow * 64 + (((kc * 4 + rg) ^ (krow & 7)) * 8));
    }

    f32x4 s[2][4];
#pragma unroll
    for (int m = 0; m < 2; m++)
#pragma unroll
      for (int n = 0; n < 4; n++) s[m][n] = z;
#pragma unroll
    for (int kc = 0; kc < 2; kc++)
#pragma unroll
      for (int n = 0; n < 4; n++)
#pragma unroll
        for (int m = 0; m < 2; m++)
          s[m][n] = __builtin_amdgcn_mfma_f32_16x16x32_bf16(kf[n][kc], qf[m][kc], s[m][n], 0, 0, 0);

#pragma unroll
    for (int m = 0; m < 2; m++) {
      float x0 = fmaxf(fmaxf(s[m][0][0], s[m][0][1]), fmaxf(s[m][0][2], s[m][0][3]));
      float x1 = fmaxf(fmaxf(s[m][1][0], s[m][1][1]), fmaxf(s[m][1][2], s[m][1][3]));
      float x2 = fmaxf(fmaxf(s[m][2][0], s[m][2][1]), fmaxf(s[m][2][2], s[m][2][3]));
      float x3 = fmaxf(fmaxf(s[m][3][0], s[m][3][1]), fmaxf(s[m][3][2], s[m][3][3]));
      float vmax = fmaxf(fmaxf(x0, x1), fmaxf(x2, x3));
      vmax = fmaxf(vmax, __shfl_xor(vmax, 16));
      vmax = fmaxf(vmax, __shfl_xor(vmax, 32));
      const float mnew = fmaxf(mr[m], vmax);
      const float corr = __builtin_amdgcn_exp2f(mr[m] - mnew);
      mr[m] = mnew;
      float ps = 0.f;
#pragma unroll
      for (int n = 0; n < 4; n++)
#pragma unroll
        for (int i = 0; i < 4; i++) {
          const float p = __builtin_amdgcn_exp2f(s[m][n][i] - mnew);
          s[m][n][i] = p;
          ps += p;
        }
      ps += __shfl_xor(ps, 16);
      ps += __shfl_xor(ps, 32);
      lr[m] = lr[m] * corr + ps;
#pragma unroll
      for (int np = 0; np < 4; np++)
#pragma unroll
        for (int i = 0; i < 4; i++) o[m][np][i] *= corr;
#pragma unroll
      for (int n = 0; n < 4; n++) {
        bf16x4 pv;
#pragma unroll
        for (int i = 0; i < 4; i++) pv[i] = (bf16)s[m][n][i];
        *(bf16x4*)&Pl[w][m * 16 + rl][n * 16 + rg * 4] = pv;
      }
    }

    bf16x8 pf[2][2];
#pragma unroll
    for (int m = 0; m < 2; m++)
#pragma unroll
      for (int kc = 0; kc < 2; kc++)
        pf[m][kc] = *(const bf16x8*)&Pl[w][m * 16 + rl][kc * 32 + rg * 8];

    bf16x8 vf[4][2];
#pragma unroll
    for (int np = 0; np < 4; np++) {
      const int vrow = np * 16 + rl;
#pragma unroll
      for (int kc = 0; kc < 2; kc++)
        vf[np][kc] = *(const bf16x8*)(Vc + vrow * 64 + (((kc * 4 + rg) ^ (vrow & 7)) * 8));
    }

#pragma unroll
    for (int kc = 0; kc < 2; kc++)
#pragma unroll
      for (int np = 0; np < 4; np++)
#pragma unroll
        for (int m = 0; m < 2; m++)
          o[m][np] = __builtin_amdgcn_mfma_f32_16x16x32_bf16(vf[np][kc], pf[m][kc], o[m][np], 0, 0, 0);

    __syncthreads();
    cur ^= 1;
  }
#undef STAGE

#pragma unroll
  for (int m = 0; m < 2; m++) {
    const float inv = 1.f / lr[m];
    const size_t rowb = ((size_t)b * S_ + q0 + m * 16 + rl) * D_ + h * HD_;
#pragma unroll
    for (int np = 0; np < 4; np++) {
      f32x4 ov;
#pragma unroll
      for (int i = 0; i < 4; i++) ov[i] = o[m][np][i] * inv;
      *(f32x4*)(O + rowb + np * 16 + rg * 4) = ov;
    }
  }
}

// ---------------------------------------------------------------------------
// Orchestration
// ---------------------------------------------------------------------------
extern "C" void kernel_launch(void* const* d_in, const int* in_sizes, int n_in,
                              void* d_out, int out_size, void* d_ws, size_t ws_size,
                              hipStream_t stream) {
  (void)in_sizes; (void)n_in; (void)out_size; (void)ws_size;
  const float* x   = (const float*)d_in[0];
  const float* Wq  = (const float*)d_in[1];
  const float* bq  = (const float*)d_in[2];
  const float* Wk  = (const float*)d_in[3];
  const float* bk  = (const float*)d_in[4];
  const float* Wv  = (const float*)d_in[5];
  const float* bv  = (const float*)d_in[6];
  const float* g1  = (const float*)d_in[7];
  const float* be1 = (const float*)d_in[8];
  const float* g2  = (const float*)d_in[9];
  const float* be2 = (const float*)d_in[10];
  const float* W1  = (const float*)d_in[11];
  const float* b1  = (const float*)d_in[12];
  const float* W2  = (const float*)d_in[13];
  const float* b2  = (const float*)d_in[14];
  float* out = (float*)d_out;

  // ws layout (bytes). wq/wk/wv transposed weights contiguous => fused QKV.
  char* p = (char*)d_ws;
  const size_t MB = (size_t)1 << 20;
  bf16*  wqkv = (bf16*)(p + 0 * MB);    // (3072,1024) bf16 (N,K), rows: Wq^T|Wk^T|Wv^T
  bf16*  w1t  = (bf16*)(p + 6 * MB);    // (4096,1024)
  bf16*  w2t  = (bf16*)(p + 14 * MB);   // (1024,4096)
  bf16*  hb   = (bf16*)(p + 22 * MB);   // LN1 out (8192,1024)
  bf16*  qb   = (bf16*)(p + 38 * MB);   // q * log2e/8
  bf16*  kb   = (bf16*)(p + 54 * MB);
  bf16*  vt   = (bf16*)(p + 70 * MB);   // V^T (B,H,HD,S)
  float* at   = (float*)(p + 86 * MB);  // attn out fp32 (8192,1024)
  bf16*  fb   = (bf16*)(p + 118 * MB);  // LN2 out
  bf16*  ff1  = (bf16*)(p + 22 * MB);   // relu(f@W1+b1) (8192,4096), aliased

  const dim3 tb(32, 8);
  wcast_t<<<dim3(32, 32),  tb, 0, stream>>>(Wq, wqkv,                1024, 1024);
  wcast_t<<<dim3(32, 32),  tb, 0, stream>>>(Wk, wqkv + 1024 * 1024,  1024, 1024);
  wcast_t<<<dim3(32, 32),  tb, 0, stream>>>(Wv, wqkv + 2048 * 1024,  1024, 1024);
  wcast_t<<<dim3(128, 32), tb, 0, stream>>>(W1, w1t, 1024, 4096);
  wcast_t<<<dim3(32, 128), tb, 0, stream>>>(W2, w2t, 4096, 1024);

  ln_fused<<<MTOT, 256, 0, stream>>>(x, nullptr, g1, be1, hb);

  // QKV: M=8192, N=3072, K=1024 -> 32x12 = 384 blocks (div by 8)
  gemm256<5><<<384, 512, 0, stream>>>(hb, wqkv, nullptr, nullptr, nullptr,
                                      bq, bk, bv, qb, kb, vt, MTOT, 3072, 1024);

  attn_fwd<<<dim3(8, 64), 512, 0, stream>>>(qb, kb, vt, at);

  ln_fused<<<MTOT, 256, 0, stream>>>(at, x, g2, be2, fb);

  // FFN1: 32x16 = 512 blocks; FFN2: 32x4 = 128 blocks
  gemm256<3><<<512, 512, 0, stream>>>(fb, w1t, b1, ff1, nullptr,
                                      nullptr, nullptr, nullptr, nullptr, nullptr, nullptr,
                                      MTOT, 4096, 1024);
  gemm256<4><<<128, 512, 0, stream>>>(ff1, w2t, b2, out, fb,
                                      nullptr, nullptr, nullptr, nullptr, nullptr, nullptr,
                                      MTOT, 1024, 4096);
}

// Round 6
// 531.150 us; speedup vs baseline: 1.0840x; 1.0840x over previous
//
#include <hip/hip_runtime.h>
#include <hip/hip_bf16.h>
#include <cstdint>
#include <cstddef>

// Problem constants
#define B_   4
#define S_   2048
#define D_   1024
#define H_   16
#define HD_  64
#define FF_  4096
#define MTOT (B_*S_)   // 8192 rows

typedef __bf16 bf16;
typedef bf16  bf16x8 __attribute__((ext_vector_type(8)));
typedef bf16  bf16x4 __attribute__((ext_vector_type(4)));
typedef float f32x4  __attribute__((ext_vector_type(4)));

#define LOG2E 1.44269504088896340736f

// ---------------------------------------------------------------------------
// async global -> LDS, 16B per lane. LDS dst wave-uniform base + lane*16;
// global source per-lane. (learn_hip m97/m173 pattern)
// ---------------------------------------------------------------------------
__device__ __forceinline__ void async16(const bf16* g, bf16* l) {
  __builtin_amdgcn_global_load_lds(
      (const __attribute__((address_space(1))) unsigned int*)g,
      (__attribute__((address_space(3))) unsigned int*)l,
      16, 0, 0);
}

template <int N> __device__ __forceinline__ void vmw() {
  if constexpr (N == 4)      asm volatile("s_waitcnt vmcnt(4)" ::: "memory");
  else if constexpr (N == 3) asm volatile("s_waitcnt vmcnt(3)" ::: "memory");
  else                       asm volatile("s_waitcnt vmcnt(0)" ::: "memory");
}

// ---------------------------------------------------------------------------
// Weight cast+transpose: W (K x N) fp32 -> Wt (N x K) bf16
// ---------------------------------------------------------------------------
__global__ void wcast_t(const float* __restrict__ W, bf16* __restrict__ Wt,
                        int K, int N) {
  __shared__ float t[32][33];
  const int k0 = blockIdx.y * 32, n0 = blockIdx.x * 32;
  const int tx = threadIdx.x, ty = threadIdx.y;
#pragma unroll
  for (int r = ty; r < 32; r += 8)
    t[r][tx] = W[(size_t)(k0 + r) * N + n0 + tx];
  __syncthreads();
#pragma unroll
  for (int r = ty; r < 32; r += 8)
    Wt[(size_t)(n0 + r) * K + k0 + tx] = (bf16)t[tx][r];
}

// ---------------------------------------------------------------------------
// Fused (residual-add +) LayerNorm -> bf16.  One block per row, 256 thr.
// ---------------------------------------------------------------------------
__global__ void ln_fused(const float* __restrict__ xin, const float* __restrict__ res,
                         const float* __restrict__ gamma, const float* __restrict__ beta,
                         bf16* __restrict__ out) {
  const int row = blockIdx.x, tid = threadIdx.x;
  const int lane = tid & 63, w = tid >> 6;
  f32x4 v = *(const f32x4*)(xin + (size_t)row * D_ + tid * 4);
  if (res) {
    f32x4 r = *(const f32x4*)(res + (size_t)row * D_ + tid * 4);
    v += r;
  }
  float sum = v[0] + v[1] + v[2] + v[3];
  float sq  = v[0]*v[0] + v[1]*v[1] + v[2]*v[2] + v[3]*v[3];
#pragma unroll
  for (int d = 1; d < 64; d <<= 1) {
    sum += __shfl_xor(sum, d);
    sq  += __shfl_xor(sq, d);
  }
  __shared__ float red[8];
  if (lane == 0) { red[w] = sum; red[4 + w] = sq; }
  __syncthreads();
  sum = red[0] + red[1] + red[2] + red[3];
  sq  = red[4] + red[5] + red[6] + red[7];
  const float mu   = sum * (1.f / D_);
  const float rstd = rsqrtf(sq * (1.f / D_) - mu * mu + 1e-5f);
  f32x4 g  = *(const f32x4*)(gamma + tid * 4);
  f32x4 bt = *(const f32x4*)(beta  + tid * 4);
  bf16x4 ov;
#pragma unroll
  for (int j = 0; j < 4; j++)
    ov[j] = (bf16)((v[j] - mu) * rstd * g[j] + bt[j]);
  *(bf16x4*)(out + (size_t)row * D_ + tid * 4) = ov;
}

// ---------------------------------------------------------------------------
// Phase-interleaved 256xBN GEMM, BK=64, 8 waves, counted vmcnt (T3+T4+T5).
//
// LDS: per slot, A as [2kh][128][64] bf16 (k-half kh = k 0-31 / 32-63 of all
// 256 rows; logical (r,k) at phys [r>>1][(r&1)*32+(k&31)]; 16KB per kh,
// DMA-contiguous). Read swizzle: 16B chunk c0=(r&1)*4+rg XOR (pr&7) — the
// same involution applied to the DMA *source* (rule #21). B identical.
//
// Per K-tile T (slot s), 4 phases; stages target tile T+1 (slot s^1):
//   ph1 (kk0): ds A-kh0 frags + B frags n0/n1 | stage A-kh0(T+1) | bar | 16 MFMA
//   ph2 (kk0): ds B frags n2/n3              | stage B-kh0(T+1) | vmcnt(VMN) | bar | MFMA
//   ph3 (kk1): like ph1 with kh1
//   ph4 (kk1): like ph2 with kh1, vmcnt(VMN)
// Stagger invariant: at each vmcnt(VMN), the oldest VMN loads are exactly the
// k-half first needed after the next barrier; VMN loads stay in flight —
// vmcnt never drains to 0 in the main loop (T4). setprio(1) around each
// MFMA cluster (T5). Per-wave vmcnt + s_barrier => all waves' DMA confirmed.
//
// EPI: 3=ffn1 (bias, relu, bf16)  4=ffn2 (bias + addf residual, fp32)
//      5=qkv (3-sector: q*log2e/8 | k | v->Vt[B,H,HD,S])  (BN=256 only)
// ---------------------------------------------------------------------------
template <int EPI, int BN>
__global__ __launch_bounds__(512)
void gemm8p(const bf16* __restrict__ Ag, const bf16* __restrict__ Bg,
            const float* __restrict__ bias, void* __restrict__ Cout,
            const bf16* __restrict__ addf,
            const float* __restrict__ bq, const float* __restrict__ bk,
            const float* __restrict__ bv, bf16* __restrict__ qout,
            bf16* __restrict__ kout, bf16* __restrict__ vtout,
            int M, int N, int K) {
  constexpr int WN     = (BN == 256) ? 4 : 2;   // waves along N
  constexpr int WMR    = (BN == 256) ? 128 : 64; // wave rows
  constexpr int AFR    = WMR / 16;               // A frags / kk
  constexpr int BLOADS = BN / 128;               // B stage issues per half
  constexpr int BPHYS  = BN / 2;                 // phys rows per B kh
  constexpr int VMN    = 2 + BLOADS;

  __shared__ bf16 As[2][2][128 * 64];
  __shared__ bf16 Bs[2][2][BPHYS * 64];

  const int tid = threadIdx.x;
  const int lane = tid & 63;
  const int w = tid >> 6;
  const int wm = w / WN, wn = w % WN;
  const int rg = lane >> 4, rl = lane & 15;

  // staging lane constants (source pre-swizzle = read swizzle involution)
  const int sr    = lane >> 3;                 // phys row within 8-row slice
  const int scu   = (lane & 7) ^ sr;           // unswizzled chunk
  const int srow  = w * 16 + 2 * sr + (scu >> 2);  // logical row (per 128-blk)
  const int sksub = (scu & 3) * 8;             // k offset within 32-half

  // XCD-aware swizzle of linear block id (grid % 8 == 0 for all callers)
  const int nbn = N / BN;
  const int cpx = (int)gridDim.x >> 3;
  const int bid = (int)blockIdx.x;
  const int swz = (bid & 7) * cpx + (bid >> 3);
  const int bm = (swz / nbn) << 8;
  const int bn = (swz % nbn) * BN;

#define FRAG(arr, rr)                                                        \
  ({ const int r_ = (rr); const int pr_ = r_ >> 1;                           \
     const int c_ = ((((r_ & 1) << 2) | rg) ^ (pr_ & 7));                    \
     *(const bf16x8*)(&(arr)[pr_ * 64 + c_ * 8]); })

#define STAGE_A(oslot, kh, tt)                                               \
  { _Pragma("unroll")                                                        \
    for (int i_ = 0; i_ < 2; i_++)                                           \
      async16(Ag + (size_t)(bm + i_ * 128 + srow) * K +                      \
                  (size_t)((tt) * 64 + (kh) * 32 + sksub),                   \
              &As[oslot][kh][(i_ * 64 + w * 8) * 64]); }

#define STAGE_B(oslot, kh, tt)                                               \
  { _Pragma("unroll")                                                        \
    for (int i_ = 0; i_ < BLOADS; i_++)                                      \
      async16(Bg + (size_t)(bn + i_ * 128 + srow) * K +                      \
                  (size_t)((tt) * 64 + (kh) * 32 + sksub),                   \
              &Bs[oslot][kh][(i_ * 64 + w * 8) * 64]); }

#define BAR()                                                                \
  { __builtin_amdgcn_sched_barrier(0); __builtin_amdgcn_s_barrier();         \
    __builtin_amdgcn_sched_barrier(0); }

#define MMACL(nh, B0, B1)                                                    \
  { __builtin_amdgcn_s_setprio(1);                                           \
    _Pragma("unroll")                                                        \
    for (int mi = 0; mi < AFR; mi++) {                                       \
      acc[mi][(nh)*2+0] = __builtin_amdgcn_mfma_f32_16x16x32_bf16(           \
          af[mi], B0, acc[mi][(nh)*2+0], 0, 0, 0);                           \
      acc[mi][(nh)*2+1] = __builtin_amdgcn_mfma_f32_16x16x32_bf16(           \
          af[mi], B1, acc[mi][(nh)*2+1], 0, 0, 0);                           \
    }                                                                        \
    __builtin_amdgcn_s_setprio(0); }

#define TILE(slot, oslot, tnx)                                               \
  { bf16x8 af[AFR];                                                          \
    _Pragma("unroll")                                                        \
    for (int mi = 0; mi < AFR; mi++)                                         \
      af[mi] = FRAG(As[slot][0], wm * WMR + mi * 16 + rl);                   \
    { bf16x8 b0 = FRAG(Bs[slot][0], wn * 64 + 0  + rl);                      \
      bf16x8 b1 = FRAG(Bs[slot][0], wn * 64 + 16 + rl);                      \
      STAGE_A(oslot, 0, tnx); BAR(); MMACL(0, b0, b1); }                     \
    { bf16x8 b0 = FRAG(Bs[slot][0], wn * 64 + 32 + rl);                      \
      bf16x8 b1 = FRAG(Bs[slot][0], wn * 64 + 48 + rl);                      \
      STAGE_B(oslot, 0, tnx); vmw<VMN>(); BAR(); MMACL(1, b0, b1); }         \
    _Pragma("unroll")                                                        \
    for (int mi = 0; mi < AFR; mi++)                                         \
      af[mi] = FRAG(As[slot][1], wm * WMR + mi * 16 + rl);                   \
    { bf16x8 b0 = FRAG(Bs[slot][1], wn * 64 + 0  + rl);                      \
      bf16x8 b1 = FRAG(Bs[slot][1], wn * 64 + 16 + rl);                      \
      STAGE_A(oslot, 1, tnx); BAR(); MMACL(0, b0, b1); }                     \
    { bf16x8 b0 = FRAG(Bs[slot][1], wn * 64 + 32 + rl);                      \
      bf16x8 b1 = FRAG(Bs[slot][1], wn * 64 + 48 + rl);                      \
      STAGE_B(oslot, 1, tnx); vmw<VMN>(); BAR(); MMACL(1, b0, b1); } }

  f32x4 acc[AFR][4];
  const f32x4 z = {0.f, 0.f, 0.f, 0.f};
#pragma unroll
  for (int mi = 0; mi < AFR; mi++)
#pragma unroll
    for (int ni = 0; ni < 4; ni++) acc[mi][ni] = z;

  const int NT = K >> 6;
  // prologue: tile 0 -> slot 0, in consumption order; wait kh0, keep kh1 out
  STAGE_A(0, 0, 0); STAGE_B(0, 0, 0); STAGE_A(0, 1, 0); STAGE_B(0, 1, 0);
  vmw<VMN>();
  BAR();

  for (int it = 0; it < NT / 2; ++it) {
    const int t1 = 2 * it + 1;
    const int n2 = (t1 + 1 < NT) ? t1 + 1 : NT - 1;  // clamp keeps counts exact
    TILE(0, 1, t1);   // compute tile 2it (slot0), stage tile t1 -> slot1
    TILE(1, 0, n2);   // compute tile t1  (slot1), stage tile t1+1 -> slot0
  }
  vmw<0>();   // drain leftover prefetch before endpgm

#undef TILE
#undef MMACL
#undef BAR
#undef STAGE_B
#undef STAGE_A
#undef FRAG

  // Epilogue. C/D layout: col = lane&15, row = (lane>>4)*4 + i   [m89/m91]
#pragma unroll
  for (int mi = 0; mi < AFR; mi++) {
    const int row0 = bm + wm * WMR + mi * 16 + rg * 4;
#pragma unroll
    for (int ni = 0; ni < 4; ni++) {
      const int col = bn + wn * 64 + ni * 16 + rl;
      if (EPI == 3) {
        const float bb = bias[col];
#pragma unroll
        for (int i = 0; i < 4; i++)
          ((bf16*)Cout)[(size_t)(row0 + i) * N + col] =
              (bf16)fmaxf(acc[mi][ni][i] + bb, 0.f);
      } else if (EPI == 4) {
        const float bb = bias[col];
#pragma unroll
        for (int i = 0; i < 4; i++)
          ((float*)Cout)[(size_t)(row0 + i) * N + col] =
              acc[mi][ni][i] + bb + (float)addf[(size_t)(row0 + i) * N + col];
      } else {  // EPI == 5: qkv sectors (BN=256: block within one sector)
        const int sector = bn >> 10;
        const int cl = col & 1023;
        const float bb = (sector == 0) ? bq[cl] : (sector == 1 ? bk[cl] : bv[cl]);
#pragma unroll
        for (int i = 0; i < 4; i++) {
          const int row = row0 + i;
          const float v = acc[mi][ni][i] + bb;
          if (sector == 0) {
            qout[(size_t)row * D_ + cl] = (bf16)(v * (0.125f * LOG2E));
          } else if (sector == 1) {
            kout[(size_t)row * D_ + cl] = (bf16)v;
          } else {
            const int b = row >> 11, s = row & 2047;
            const int h = cl >> 6, hd = cl & 63;
            vtout[(((size_t)(b * H_ + h) * HD_ + hd) << 11) + s] = (bf16)v;
          }
        }
      }
    }
  }
}

// ---------------------------------------------------------------------------
// Flash attention, swapped-operand, 8 waves / block (QBLK=256, 32 q-rows/wave).
// Grid (S/256, B*H) = (8,64) = 512 blocks. (round-4 verified: 122 µs)
// ---------------------------------------------------------------------------
__global__ __launch_bounds__(512, 4)
void attn_fwd(const bf16* __restrict__ Q, const bf16* __restrict__ Kb,
              const bf16* __restrict__ Vt, float* __restrict__ O) {
  __shared__ bf16 Ks[2][64 * 64];   // [kv][hd], 8KB per buf
  __shared__ bf16 Vs[2][64 * 64];   // [hd][kv], 8KB per buf
  __shared__ bf16 Pl[8][32][72];    // per-wave P^T [q_local][kv], 36KB
  const int tid = threadIdx.x, lane = tid & 63, w = tid >> 6;
  const int rg = lane >> 4, rl = lane & 15;
  const int bh = blockIdx.y, b = bh >> 4, h = bh & 15;
  const int q0 = blockIdx.x * 256 + w * 32;

  const bf16* qp = Q + ((size_t)b * S_ + q0) * D_ + h * HD_;
  const bf16* kp = Kb + (size_t)b * S_ * D_ + h * HD_;
  const bf16* vp = Vt + (size_t)bh * HD_ * S_;

  const int sr = lane >> 3;
  const int sc = (lane & 7) ^ sr;

#define STAGE(buf, t)                                                          \
  {                                                                            \
    const int row = w * 8 + sr;                                                \
    async16(kp + (size_t)((t) * 64 + row) * D_ + sc * 8, &Ks[buf][w * 8 * 64]);\
    async16(vp + (size_t)row * S_ + (t) * 64 + sc * 8,  &Vs[buf][w * 8 * 64]); \
  }

  bf16x8 qf[2][2];
#pragma unroll
  for (int m = 0; m < 2; m++)
#pragma unroll
    for (int kc = 0; kc < 2; kc++)
      qf[m][kc] = *(const bf16x8*)(qp + (size_t)(m * 16 + rl) * D_ + kc * 32 + rg * 8);

  const f32x4 z = {0.f, 0.f, 0.f, 0.f};
  f32x4 o[2][4];
  float mr[2], lr[2];
#pragma unroll
  for (int m = 0; m < 2; m++) {
    mr[m] = -1e30f; lr[m] = 0.f;
#pragma unroll
    for (int np = 0; np < 4; np++) o[m][np] = z;
  }

  STAGE(0, 0);
  __syncthreads();

  int cur = 0;
  for (int t = 0; t < S_ / 64; ++t) {
    if (t + 1 < S_ / 64) STAGE(cur ^ 1, t + 1);
    const bf16* Kc = Ks[cur];
    const bf16* Vc = Vs[cur];

    bf16x8 kf[4][2];
#pragma unroll
    for (int n = 0; n < 4; n++) {
      const int krow = n * 16 + rl;
#pragma unroll
      for (int kc = 0; kc < 2; kc++)
        kf[n][kc] = *(const bf16x8*)(Kc + krow * 64 + (((kc * 4 + rg) ^ (krow & 7)) * 8));
    }

    f32x4 s[2][4];
#pragma unroll
    for (int m = 0; m < 2; m++)
#pragma unroll
      for (int n = 0; n < 4; n++) s[m][n] = z;
#pragma unroll
    for (int kc = 0; kc < 2; kc++)
#pragma unroll
      for (int n = 0; n < 4; n++)
#pragma unroll
        for (int m = 0; m < 2; m++)
          s[m][n] = __builtin_amdgcn_mfma_f32_16x16x32_bf16(kf[n][kc], qf[m][kc], s[m][n], 0, 0, 0);

#pragma unroll
    for (int m = 0; m < 2; m++) {
      float x0 = fmaxf(fmaxf(s[m][0][0], s[m][0][1]), fmaxf(s[m][0][2], s[m][0][3]));
      float x1 = fmaxf(fmaxf(s[m][1][0], s[m][1][1]), fmaxf(s[m][1][2], s[m][1][3]));
      float x2 = fmaxf(fmaxf(s[m][2][0], s[m][2][1]), fmaxf(s[m][2][2], s[m][2][3]));
      float x3 = fmaxf(fmaxf(s[m][3][0], s[m][3][1]), fmaxf(s[m][3][2], s[m][3][3]));
      float vmax = fmaxf(fmaxf(x0, x1), fmaxf(x2, x3));
      vmax = fmaxf(vmax, __shfl_xor(vmax, 16));
      vmax = fmaxf(vmax, __shfl_xor(vmax, 32));
      const float mnew = fmaxf(mr[m], vmax);
      const float corr = __builtin_amdgcn_exp2f(mr[m] - mnew);
      mr[m] = mnew;
      float ps = 0.f;
#pragma unroll
      for (int n = 0; n < 4; n++)
#pragma unroll
        for (int i = 0; i < 4; i++) {
          const float p = __builtin_amdgcn_exp2f(s[m][n][i] - mnew);
          s[m][n][i] = p;
          ps += p;
        }
      ps += __shfl_xor(ps, 16);
      ps += __shfl_xor(ps, 32);
      lr[m] = lr[m] * corr + ps;
#pragma unroll
      for (int np = 0; np < 4; np++)
#pragma unroll
        for (int i = 0; i < 4; i++) o[m][np][i] *= corr;
#pragma unroll
      for (int n = 0; n < 4; n++) {
        bf16x4 pv;
#pragma unroll
        for (int i = 0; i < 4; i++) pv[i] = (bf16)s[m][n][i];
        *(bf16x4*)&Pl[w][m * 16 + rl][n * 16 + rg * 4] = pv;
      }
    }

    bf16x8 pf[2][2];
#pragma unroll
    for (int m = 0; m < 2; m++)
#pragma unroll
      for (int kc = 0; kc < 2; kc++)
        pf[m][kc] = *(const bf16x8*)&Pl[w][m * 16 + rl][kc * 32 + rg * 8];

    bf16x8 vf[4][2];
#pragma unroll
    for (int np = 0; np < 4; np++) {
      const int vrow = np * 16 + rl;
#pragma unroll
      for (int kc = 0; kc < 2; kc++)
        vf[np][kc] = *(const bf16x8*)(Vc + vrow * 64 + (((kc * 4 + rg) ^ (vrow & 7)) * 8));
    }

#pragma unroll
    for (int kc = 0; kc < 2; kc++)
#pragma unroll
      for (int np = 0; np < 4; np++)
#pragma unroll
        for (int m = 0; m < 2; m++)
          o[m][np] = __builtin_amdgcn_mfma_f32_16x16x32_bf16(vf[np][kc], pf[m][kc], o[m][np], 0, 0, 0);

    __syncthreads();
    cur ^= 1;
  }
#undef STAGE

#pragma unroll
  for (int m = 0; m < 2; m++) {
    const float inv = 1.f / lr[m];
    const size_t rowb = ((size_t)b * S_ + q0 + m * 16 + rl) * D_ + h * HD_;
#pragma unroll
    for (int np = 0; np < 4; np++) {
      f32x4 ov;
#pragma unroll
      for (int i = 0; i < 4; i++) ov[i] = o[m][np][i] * inv;
      *(f32x4*)(O + rowb + np * 16 + rg * 4) = ov;
    }
  }
}

// ---------------------------------------------------------------------------
// Orchestration
// ---------------------------------------------------------------------------
extern "C" void kernel_launch(void* const* d_in, const int* in_sizes, int n_in,
                              void* d_out, int out_size, void* d_ws, size_t ws_size,
                              hipStream_t stream) {
  (void)in_sizes; (void)n_in; (void)out_size; (void)ws_size;
  const float* x   = (const float*)d_in[0];
  const float* Wq  = (const float*)d_in[1];
  const float* bq  = (const float*)d_in[2];
  const float* Wk  = (const float*)d_in[3];
  const float* bk  = (const float*)d_in[4];
  const float* Wv  = (const float*)d_in[5];
  const float* bv  = (const float*)d_in[6];
  const float* g1  = (const float*)d_in[7];
  const float* be1 = (const float*)d_in[8];
  const float* g2  = (const float*)d_in[9];
  const float* be2 = (const float*)d_in[10];
  const float* W1  = (const float*)d_in[11];
  const float* b1  = (const float*)d_in[12];
  const float* W2  = (const float*)d_in[13];
  const float* b2  = (const float*)d_in[14];
  float* out = (float*)d_out;

  // ws layout (bytes). wq/wk/wv transposed weights contiguous => fused QKV.
  char* p = (char*)d_ws;
  const size_t MB = (size_t)1 << 20;
  bf16*  wqkv = (bf16*)(p + 0 * MB);    // (3072,1024) bf16 (N,K), rows: Wq^T|Wk^T|Wv^T
  bf16*  w1t  = (bf16*)(p + 6 * MB);    // (4096,1024)
  bf16*  w2t  = (bf16*)(p + 14 * MB);   // (1024,4096)
  bf16*  hb   = (bf16*)(p + 22 * MB);   // LN1 out (8192,1024)
  bf16*  qb   = (bf16*)(p + 38 * MB);   // q * log2e/8
  bf16*  kb   = (bf16*)(p + 54 * MB);
  bf16*  vt   = (bf16*)(p + 70 * MB);   // V^T (B,H,HD,S)
  float* at   = (float*)(p + 86 * MB);  // attn out fp32 (8192,1024)
  bf16*  fb   = (bf16*)(p + 118 * MB);  // LN2 out
  bf16*  ff1  = (bf16*)(p + 22 * MB);   // relu(f@W1+b1) (8192,4096), aliased

  const dim3 tb(32, 8);
  wcast_t<<<dim3(32, 32),  tb, 0, stream>>>(Wq, wqkv,                1024, 1024);
  wcast_t<<<dim3(32, 32),  tb, 0, stream>>>(Wk, wqkv + 1024 * 1024,  1024, 1024);
  wcast_t<<<dim3(32, 32),  tb, 0, stream>>>(Wv, wqkv + 2048 * 1024,  1024, 1024);
  wcast_t<<<dim3(128, 32), tb, 0, stream>>>(W1, w1t, 1024, 4096);
  wcast_t<<<dim3(32, 128), tb, 0, stream>>>(W2, w2t, 4096, 1024);

  ln_fused<<<MTOT, 256, 0, stream>>>(x, nullptr, g1, be1, hb);

  // QKV: 32 x 12 = 384 blocks (256x256 tiles)
  gemm8p<5, 256><<<384, 512, 0, stream>>>(hb, wqkv, nullptr, nullptr, nullptr,
                                          bq, bk, bv, qb, kb, vt, MTOT, 3072, 1024);

  attn_fwd<<<dim3(8, 64), 512, 0, stream>>>(qb, kb, vt, at);

  ln_fused<<<MTOT, 256, 0, stream>>>(at, x, g2, be2, fb);

  // FFN1: 32 x 16 = 512 blocks (256x256). FFN2: 32 x 8 = 256 blocks (256x128).
  gemm8p<3, 256><<<512, 512, 0, stream>>>(fb, w1t, b1, ff1, nullptr,
                                          nullptr, nullptr, nullptr, nullptr, nullptr, nullptr,
                                          MTOT, 4096, 1024);
  gemm8p<4, 128><<<256, 512, 0, stream>>>(ff1, w2t, b2, out, fb,
                                          nullptr, nullptr, nullptr, nullptr, nullptr, nullptr,
                                          MTOT, 1024, 4096);
}